// Round 13
// baseline (68.618 us; speedup 1.0000x reference)
//
#include <hip/hip_runtime.h>

// casConv2d: B=1, C=128, H=W=32, OC=128, K=3, pad=1, stride=1.
// L = 1024, CKK = 1152 = 36 exact 32-tap chunks (reference front-pad chunk == 0).
//
// Round-21. R12 (register partials, no vbuf) = 67.7, best. Budget: fill 40.3
// + overhead ~11.4 + wtrans+launch ~3 + fused ~13. Pipe budgets per CU: W
// L2-stream 4.4us (invariant: every CU needs all 576KB W), x-LDS ~2-4us,
// FMA 1.9us -> overlapped floor ~7; measured 13 -> pipes mostly serial per
// wave (1-deep W prefetch, no scheduler hint).
//
// R13 = R12 + two untried levers, numerics frozen:
//  (1) 3-buffer W rotation with all 3 buffers issued BEFORE the x-prologue
//      (2 chunk-steps of L2 latency cover; R11 only tested this on the
//      vbuf-dominated structure);
//  (2) s_setprio(1) around each chunk's LDS+FMA cluster (T5: barrier-free
//      independent waves = the attn-like regime where setprio measured +4-7%).
// FMA chains, group sums, exchanges, minmax, quant, stores verbatim R12 ->
// bit-identical, absmax 0.03515625 expected.
// Pre-commit: if |delta| < 1.5us, declare ROOFLINE next round.
#define L_    1024
#define CKK_  1152
#define QMAX_ 255.0f
#define NCH   36

static __device__ __forceinline__ float4 f4add(float4 a, float4 b) {
    return make_float4(a.x + b.x, a.y + b.y, a.z + b.z, a.w + b.w);
}

// ---- W transpose: w[oc][1152] -> wt4[tq][oc] (tq = tap quad, 288x128 f4) ----
__global__ __launch_bounds__(256) void wtrans(
    const float* __restrict__ w, float* __restrict__ wt)
{
    const int e  = blockIdx.x * 256 + threadIdx.x;   // 36864 float4 slots
    const int oc = e / 288, tq = e - 288 * oc;
    const float4 v = ((const float4*)(w + oc * CKK_))[tq];   // coalesced read
    ((float4*)wt)[tq * 128 + oc] = v;                        // scattered write (L2)
}

template <bool WT>
__global__ __launch_bounds__(512) void fused_cas(
    const float* __restrict__ x,      // [128][32][32]
    const float* __restrict__ w,      // [128][1152]        (WT=false path)
    const float4* __restrict__ wt4,   // [288][128] float4  (WT=true path)
    const float* __restrict__ bias,   // [128]
    float* __restrict__ out)          // [128][1024]
{
    __shared__ __align__(16) float  xs[NCH * 32 * 4];   // [j][tap][px], 18 KB
    __shared__ __align__(16) float4 gx[4][128];         // group exchange, 8 KB
    __shared__ float red[8][4];                         // per-wave {mn0,mx0,mn1,mx1}
    __shared__ float spar4[4][3];                       // [px]{sc,zp,iv}

    const int t   = threadIdx.x;                        // 0..511
    const int b   = blockIdx.x;
    const int oc  = t & 127;
    const int g   = t >> 7;            // chunk-ownership group (4 x 2 waves)
    const int ppe = g & 1;             // epilogue px-pair (threads 0..255)
    const int oh  = b >> 3;            // all 4 px share one output row
    const int ow0 = (b & 7) * 4;
    const int l0  = b * 4;
    const int jb  = g * 9;

    const float4* wrow = (const float4*)(w + oc * CKK_);

    auto load8 = [&](float4* dst, int j) {
#pragma unroll
        for (int k4 = 0; k4 < 8; ++k4)
            dst[k4] = WT ? wt4[(j * 8 + k4) * 128 + oc] : wrow[j * 8 + k4];
    };

    // (1) issue chunks jb..jb+2 W loads FIRST: latency hides under x staging
    float4 wA[8], wB[8], wC[8];
    load8(wA, jb + 0);
    load8(wB, jb + 1);
    load8(wC, jb + 2);

    // ---- prologue: stage ALL x for this block (4608 elems = 9/thread) ----
    for (int i = 0; i < 9; ++i) {
        const int e   = i * 512 + t;
        const int j   = e >> 7;            // chunk
        const int tap = (e >> 2) & 31;
        const int px  = e & 3;
        const int d   = j * 32 + tap;
        const int c   = d / 9, r = d - 9 * c;
        const int kh  = r / 3, kw = r - 3 * kh;
        const int iy  = oh + kh - 1, ix = ow0 + px + kw - 1;
        const bool ok = ((unsigned)iy < 32u) & ((unsigned)ix < 32u);
        const float vv = x[ok ? (c * 1024 + iy * 32 + ix) : 0];
        xs[e] = ok ? vv : 0.f;
    }
    __syncthreads();

    // ---- main loop: group g owns chunks [jb, jb+9); partials in registers ----
    auto chunk = [&](int j, const float4* wreg) -> float4 {
        float a0 = 0.f, a1 = 0.f, a2 = 0.f, a3 = 0.f;
        const float4* xj = (const float4*)(xs + j * 128);  // [tap] -> 4 px
        __builtin_amdgcn_s_setprio(1);                     // (2) favor compute wave
#pragma unroll
        for (int k4 = 0; k4 < 8; ++k4) {
            const float4 wv = wreg[k4];
            const float4 x0 = xj[4 * k4 + 0];
            const float4 x1 = xj[4 * k4 + 1];
            const float4 x2 = xj[4 * k4 + 2];
            const float4 x3 = xj[4 * k4 + 3];
            a0 = fmaf(wv.x, x0.x, a0); a1 = fmaf(wv.x, x0.y, a1);
            a2 = fmaf(wv.x, x0.z, a2); a3 = fmaf(wv.x, x0.w, a3);
            a0 = fmaf(wv.y, x1.x, a0); a1 = fmaf(wv.y, x1.y, a1);
            a2 = fmaf(wv.y, x1.z, a2); a3 = fmaf(wv.y, x1.w, a3);
            a0 = fmaf(wv.z, x2.x, a0); a1 = fmaf(wv.z, x2.y, a1);
            a2 = fmaf(wv.z, x2.z, a2); a3 = fmaf(wv.z, x2.w, a3);
            a0 = fmaf(wv.w, x3.x, a0); a1 = fmaf(wv.w, x3.y, a1);
            a2 = fmaf(wv.w, x3.z, a2); a3 = fmaf(wv.w, x3.w, a3);
        }
        __builtin_amdgcn_s_setprio(0);
        return make_float4(a0, a1, a2, a3);
    };

    float4 p0, p1, p2, p3, p4, p5, p6, p7, p8;   // named -> static, no scratch
    p0 = chunk(jb + 0, wA); load8(wA, jb + 3);
    p1 = chunk(jb + 1, wB); load8(wB, jb + 4);
    p2 = chunk(jb + 2, wC); load8(wC, jb + 5);
    p3 = chunk(jb + 3, wA); load8(wA, jb + 6);
    p4 = chunk(jb + 4, wB); load8(wB, jb + 7);
    p5 = chunk(jb + 5, wC); load8(wC, jb + 8);
    p6 = chunk(jb + 6, wA);
    p7 = chunk(jb + 7, wB);
    p8 = chunk(jb + 8, wC);

    // group sum, j ascending within group
    float4 gs = p0;
    gs = f4add(gs, p1); gs = f4add(gs, p2); gs = f4add(gs, p3);
    gs = f4add(gs, p4); gs = f4add(gs, p5); gs = f4add(gs, p6);
    gs = f4add(gs, p7); gs = f4add(gs, p8);
    gx[g][oc] = gs;
    __syncthreads();

    // ---- totals + minmax (threads 0..255; g-ascending cross-group sum) ----
    float t0 = 0.f, t1 = 0.f;
    float mn0 = 0.f, mx0 = 0.f, mn1 = 0.f, mx1 = 0.f;
    const int wv = t >> 6;                  // 0..7
    if (t < 256) {
        float4 s = gx[0][oc];
        s = f4add(s, gx[1][oc]);
        s = f4add(s, gx[2][oc]);
        s = f4add(s, gx[3][oc]);
        const float bval = bias[oc];
        t0 = ((ppe == 0) ? s.x : s.z) + bval;
        t1 = ((ppe == 0) ? s.y : s.w) + bval;

        mn0 = t0; mx0 = t0; mn1 = t1; mx1 = t1;
#pragma unroll
        for (int off = 32; off > 0; off >>= 1) {
            mn0 = fminf(mn0, __shfl_xor(mn0, off));
            mx0 = fmaxf(mx0, __shfl_xor(mx0, off));
            mn1 = fminf(mn1, __shfl_xor(mn1, off));
            mx1 = fmaxf(mx1, __shfl_xor(mx1, off));
        }
        if ((t & 63) == 0) {
            red[wv][0] = mn0; red[wv][1] = mx0;
            red[wv][2] = mn1; red[wv][3] = mx1;
        }
    }
    __syncthreads();
    if ((t & 63) == 0 && (wv & 1) == 0 && wv < 4) {  // waves 0,2 finalize ppe
        const int pw = wv ^ 1;
        const float amn0 = fminf(mn0, red[pw][0]);
        const float amx0 = fmaxf(mx0, red[pw][1]);
        const float amn1 = fminf(mn1, red[pw][2]);
        const float amx1 = fmaxf(mx1, red[pw][3]);
        {
            const float sv = (amx0 - amn0) / QMAX_;
            float z = -amn0 / sv;
            z = fmaxf(z, 0.f);      // fmaxf(NaN,0)=0 matches where(isnan,0)
            z = fminf(z, QMAX_);
            z = truncf(z);
            spar4[2 * ppe + 0][0] = sv; spar4[2 * ppe + 0][1] = z;
            spar4[2 * ppe + 0][2] = 1.0f / sv;
        }
        {
            const float sv = (amx1 - amn1) / QMAX_;
            float z = -amn1 / sv;
            z = fmaxf(z, 0.f);
            z = fminf(z, QMAX_);
            z = truncf(z);
            spar4[2 * ppe + 1][0] = sv; spar4[2 * ppe + 1][1] = z;
            spar4[2 * ppe + 1][2] = 1.0f / sv;
        }
    }
    __syncthreads();

    // ---- fake-quant of register-held partials (all threads, j asc in group) ----
    {
        const float scx = spar4[0][0], zpx = spar4[0][1], ivx = spar4[0][2];
        const float scy = spar4[1][0], zpy = spar4[1][1], ivy = spar4[1][2];
        const float scz = spar4[2][0], zpz = spar4[2][1], ivz = spar4[2][2];
        const float scw = spar4[3][0], zpw = spar4[3][1], ivw = spar4[3][2];

        float qx = 0.f, qy = 0.f, qz = 0.f, qw = 0.f;
        auto qstep = [&](const float4 p) {
            float n;
            n = rintf(p.x * ivx) + zpx; n = fminf(fmaxf(n, 0.f), QMAX_); qx += (n - zpx) * scx;
            n = rintf(p.y * ivy) + zpy; n = fminf(fmaxf(n, 0.f), QMAX_); qy += (n - zpy) * scy;
            n = rintf(p.z * ivz) + zpz; n = fminf(fmaxf(n, 0.f), QMAX_); qz += (n - zpz) * scz;
            n = rintf(p.w * ivw) + zpw; n = fminf(fmaxf(n, 0.f), QMAX_); qw += (n - zpw) * scw;
        };
        qstep(p0); qstep(p1); qstep(p2); qstep(p3); qstep(p4);
        qstep(p5); qstep(p6); qstep(p7); qstep(p8);

        gx[g][oc] = make_float4(qx, qy, qz, qw);   // reuse exchange buffer
    }
    __syncthreads();

    if (t < 128) {
        float4 f = gx[0][t];
        f = f4add(f, gx[1][t]);
        f = f4add(f, gx[2][t]);
        f = f4add(f, gx[3][t]);
        *(float4*)(out + (size_t)t * L_ + l0) = f;
    }
}

extern "C" void kernel_launch(void* const* d_in, const int* in_sizes, int n_in,
                              void* d_out, int out_size, void* d_ws, size_t ws_size,
                              hipStream_t stream) {
    const float* x    = (const float*)d_in[0];  // 128*32*32
    const float* w    = (const float*)d_in[1];  // 128*1152
    const float* bias = (const float*)d_in[2];  // 128
    float* out = (float*)d_out;                 // 128*1024
    float* ws  = (float*)d_ws;

    const size_t wt_need = (size_t)288 * 128 * 16;   // 576 KB
    if (ws_size >= wt_need) {
        wtrans<<<144, 256, 0, stream>>>(w, ws);
        fused_cas<true><<<256, 512, 0, stream>>>(
            x, w, (const float4*)ws, bias, out);
    } else {
        fused_cas<false><<<256, 512, 0, stream>>>(
            x, w, nullptr, bias, out);
    }
}